// Round 1
// baseline (33844.266 us; speedup 1.0000x reference)
//
#include <hip/hip_runtime.h>
#include <math.h>

// Problem constants
#define NB 256   // batch
#define NT 512   // time steps
#define NF 65    // features (x); xm = concat(x, mask) -> 130
#define NH 512   // hidden
#define NCL 8    // clusters (one per XCD heuristically: cl = bid & 7)
#define BPC 32   // blocks per cluster (each owns 16 hidden units)
#define BCL 32   // batch rows per cluster

typedef __attribute__((ext_vector_type(8))) _Float16 f16x8;
typedef __attribute__((ext_vector_type(4))) float   f32x4;

// Persistent device scratch (avoids any dependence on ws_size).
// g_cnt + h buffers are re-zeroed by init_kernel every launch -> deterministic.
__device__ __align__(16) int      g_cnt[16];
__device__ __align__(16) _Float16 g_h1[NCL * 2 * BCL * NH];   // [cl][parity][32][512]
__device__ __align__(16) _Float16 g_h2[NCL * 2 * BCL * NH];
__device__ __align__(16) float    g_stats[NCL * BCL * BPC * 2]; // per-block LN partials
__device__ __align__(16) float    g_pool[NB * NH];
__device__ __align__(16) float    g_Wt[NH * (NH / 2)];          // W_proj transposed

__device__ __forceinline__ float sigm(float v)  { return 1.f / (1.f + __expf(-v)); }
__device__ __forceinline__ float tanh_(float v) { return 1.f - 2.f / (1.f + __expf(2.f * v)); }

__global__ void init_kernel(const float* __restrict__ Wp) {
  int i0 = blockIdx.x * blockDim.x + threadIdx.x;
  int n  = gridDim.x * blockDim.x;
  for (int i = i0; i < 16; i += n) g_cnt[i] = 0;
  for (int i = i0; i < NCL * 2 * BCL * NH; i += n) {
    g_h1[i] = (_Float16)0.f;
    g_h2[i] = (_Float16)0.f;
  }
  for (int i = i0; i < NH * (NH / 2); i += n)
    g_Wt[i] = Wp[(i & 255) * NH + (i >> 8)];   // Wt[u][o] = Wp[o][u]
}

// Persistent fused 2-layer GRU + online LayerNorm/pooling.
// grid = 256 blocks (1/CU, LDS-pinned), block = 256 threads (4 waves).
// Wave job map (m = batch M-tile 0/1, g = gate r/z/n):
//   w0: (0,r),(1,z)   w1: (0,z),(1,n)   w2: (0,n) + gate-math m0   w3: (1,r) + gate-math m1
__global__ __launch_bounds__(256, 1) void gru_main(
    const float* __restrict__ x,    const int*   __restrict__ mask,
    const float* __restrict__ Wih0, const float* __restrict__ Whh0,
    const float* __restrict__ bih0, const float* __restrict__ bhh0,
    const float* __restrict__ Wih1, const float* __restrict__ Whh1,
    const float* __restrict__ bih1, const float* __restrict__ bhh1,
    const float* __restrict__ lng,  const float* __restrict__ lnb) {
  extern __shared__ char lds[];
  _Float16* wHH0 = (_Float16*)lds;              // [3][16][64][8] f16 frag-packed, 48KB
  _Float16* wIH1 = (_Float16*)(lds + 49152);
  _Float16* wHH1 = (_Float16*)(lds + 98304);
  float*    exch = (float*)(lds + 147456);      // 8 tiles * 16*16 f32 = 8KB

  const int tid = threadIdx.x, bid = blockIdx.x;
  const int cl = bid & 7, q = bid >> 3;
  const int j0 = q * 16;                        // this block's hidden-unit base
  const int w = tid >> 6, l = tid & 63, l15 = l & 15, lgp = l >> 4;

  // Pack weight slices into MFMA B-fragment order:
  // B[k][n] = W[g*512 + j0 + n][k]; frag elem (c, lane, j) <-> k = c*32 + (lane>>4)*8 + j, n = lane&15
  for (int e = tid; e < 3 * 16 * NH; e += 256) {
    int k = e & 511, ru = e >> 9;
    int g = ru >> 4, u = ru & 15;
    int src = (g * NH + j0 + u) * NH + k;
    int dst = ((g * 16 + (k >> 5)) * 64 + ((((k >> 3) & 3) << 4) | u)) * 8 + (k & 7);
    wHH0[dst] = (_Float16)Whh0[src];
    wIH1[dst] = (_Float16)Wih1[src];
    wHH1[dst] = (_Float16)Whh1[src];
  }

  int mA = 0, gA = 0, mB = 0, gB = 0; bool two = false;
  if (w == 0)      { mA = 0; gA = 0; mB = 1; gB = 1; two = true; }
  else if (w == 1) { mA = 0; gA = 1; mB = 1; gB = 2; two = true; }
  else if (w == 2) { mA = 0; gA = 2; }
  else             { mA = 1; gA = 0; }

  // W_ih0 slice fragments in registers (K=130 padded to 160)
  f16x8 wfA[5], wfB[5];
  #pragma unroll
  for (int c = 0; c < 5; c++) {
    #pragma unroll
    for (int j = 0; j < 8; j++) {
      int k = c * 32 + (lgp << 3) + j;
      float v1 = (k < 130) ? Wih0[(gA * NH + j0 + l15) * 130 + k] : 0.f;
      wfA[c][j] = (_Float16)v1;
      float v2 = (two && k < 130) ? Wih0[(gB * NH + j0 + l15) * 130 + k] : 0.f;
      wfB[c][j] = (_Float16)v2;
    }
  }

  // Gate-math wave persistent state
  const int ucol = j0 + l15;
  float cbr0 = 0, cbz0 = 0, bin0 = 0, bhn0 = 0, cbr1 = 0, cbz1 = 0, bin1 = 0, bhn1 = 0;
  if (w >= 2) {
    cbr0 = bih0[ucol] + bhh0[ucol];
    cbz0 = bih0[NH + ucol] + bhh0[NH + ucol];
    bin0 = bih0[2 * NH + ucol];
    bhn0 = bhh0[2 * NH + ucol];
    cbr1 = bih1[ucol] + bhh1[ucol];
    cbz1 = bih1[NH + ucol] + bhh1[NH + ucol];
    bin1 = bih1[2 * NH + ucol];
    bhn1 = bhh1[2 * NH + ucol];
  }
  float h1loc[4] = {0, 0, 0, 0}, h2loc[4] = {0, 0, 0, 0};
  float A1[4] = {0, 0, 0, 0}, A0[4] = {0, 0, 0, 0}, lastc[4] = {0, 0, 0, 0};

  // K=512 GEMM: A rows = batch (f16 [32][512] in device-global), B resident in LDS frags
  auto gemm512 = [&](const _Float16* __restrict__ A, int m, const _Float16* __restrict__ Bf,
                     f32x4 acc) -> f32x4 {
    const _Float16* ap = A + (m * 16 + l15) * NH + (lgp << 3);
    f16x8 af[16];
    #pragma unroll
    for (int c = 0; c < 16; c++) af[c] = *(const f16x8*)(ap + c * 32);
    #pragma unroll
    for (int c = 0; c < 16; c++) {
      f16x8 bv = *(const f16x8*)(Bf + (c * 64 + l) * 8);
      acc = __builtin_amdgcn_mfma_f32_16x16x32_f16(af[c], bv, acc, 0, 0, 0);
    }
    return acc;
  };

  // Layer-0 input projection: A = concat(x, mask)[t] built on the fly
  auto gemmih0 = [&](int m, const f16x8* wf, f32x4 acc, int t) -> f32x4 {
    int b = cl * BCL + m * 16 + l15;
    const float* xb = x + ((long)b * NT + t) * NF;
    const int*   mb = mask + ((long)b * NT + t) * NF;
    #pragma unroll
    for (int c = 0; c < 5; c++) {
      f16x8 av;
      #pragma unroll
      for (int j = 0; j < 8; j++) {
        int k = c * 32 + (lgp << 3) + j;
        float v = 0.f;
        if (k < NF) v = xb[k];
        else if (k < 2 * NF) v = (float)mb[k - NF];
        av[j] = (_Float16)v;
      }
      acc = __builtin_amdgcn_mfma_f32_16x16x32_f16(av, wf[c], acc, 0, 0, 0);
    }
    return acc;
  };

  auto storeTile = [&](int slot, f32x4 a) {
    float* et = exch + slot * 256;
    #pragma unroll
    for (int r = 0; r < 4; r++) et[(lgp * 4 + r) * 16 + l15] = a[r];
  };

  __syncthreads();

  for (int t = 0; t < NT; ++t) {
    const _Float16* h1p = g_h1 + (cl * 2 + ((t + 1) & 1)) * BCL * NH;
    _Float16*       h1c = g_h1 + (cl * 2 + (t & 1)) * BCL * NH;
    const _Float16* h2p = g_h2 + (cl * 2 + ((t + 1) & 1)) * BCL * NH;
    _Float16*       h2c = g_h2 + (cl * 2 + (t & 1)) * BCL * NH;
    f32x4 z4 = {0.f, 0.f, 0.f, 0.f};

    // ---- phase A: layer-0 gates ----
    if (gA < 2) {
      f32x4 a = gemmih0(mA, wfA, z4, t);
      a = gemm512(h1p, mA, wHH0 + gA * 8192, a);
      storeTile(mA * 4 + gA, a);
    } else {
      f32x4 ai = gemmih0(mA, wfA, z4, t);
      f32x4 ah = gemm512(h1p, mA, wHH0 + 2 * 8192, z4);
      storeTile(mA * 4 + 2, ai); storeTile(mA * 4 + 3, ah);
    }
    if (two) {
      if (gB < 2) {
        f32x4 a = gemmih0(mB, wfB, z4, t);
        a = gemm512(h1p, mB, wHH0 + gB * 8192, a);
        storeTile(mB * 4 + gB, a);
      } else {
        f32x4 ai = gemmih0(mB, wfB, z4, t);
        f32x4 ah = gemm512(h1p, mB, wHH0 + 2 * 8192, z4);
        storeTile(mB * 4 + 2, ai); storeTile(mB * 4 + 3, ah);
      }
    }
    __syncthreads();

    if (w >= 2) {  // gate math layer 0, update h1 slice
      int m = w - 2;
      const float* eb = exch + m * 4 * 256;
      #pragma unroll
      for (int r = 0; r < 4; r++) {
        int ro = (lgp * 4 + r) * 16 + l15;
        float rg = sigm(eb[ro] + cbr0);
        float zg = sigm(eb[256 + ro] + cbz0);
        float ng = tanh_(eb[512 + ro] + bin0 + rg * (eb[768 + ro] + bhn0));
        float hn = (1.f - zg) * ng + zg * h1loc[r];
        h1loc[r] = hn;
        h1c[(m * 16 + lgp * 4 + r) * NH + ucol] = (_Float16)hn;
      }
    }
    __threadfence();
    __syncthreads();
    if (tid == 0) {  // cluster barrier A (publishes h1(t))
      __hip_atomic_fetch_add(&g_cnt[cl * 2], 1, __ATOMIC_RELEASE, __HIP_MEMORY_SCOPE_AGENT);
      while (__hip_atomic_load(&g_cnt[cl * 2], __ATOMIC_ACQUIRE, __HIP_MEMORY_SCOPE_AGENT) <
             BPC * (t + 1))
        __builtin_amdgcn_s_sleep(1);
    }
    __syncthreads();

    // ---- phase B: layer-1 gates ----
    if (gA < 2) {
      f32x4 a = gemm512(h1c, mA, wIH1 + gA * 8192, z4);
      a = gemm512(h2p, mA, wHH1 + gA * 8192, a);
      storeTile(mA * 4 + gA, a);
    } else {
      f32x4 ai = gemm512(h1c, mA, wIH1 + 2 * 8192, z4);
      f32x4 ah = gemm512(h2p, mA, wHH1 + 2 * 8192, z4);
      storeTile(mA * 4 + 2, ai); storeTile(mA * 4 + 3, ah);
    }
    if (two) {
      if (gB < 2) {
        f32x4 a = gemm512(h1c, mB, wIH1 + gB * 8192, z4);
        a = gemm512(h2p, mB, wHH1 + gB * 8192, a);
        storeTile(mB * 4 + gB, a);
      } else {
        f32x4 ai = gemm512(h1c, mB, wIH1 + 2 * 8192, z4);
        f32x4 ah = gemm512(h2p, mB, wHH1 + 2 * 8192, z4);
        storeTile(mB * 4 + 2, ai); storeTile(mB * 4 + 3, ah);
      }
    }
    __syncthreads();

    if (w >= 2) {  // gate math layer 1, update h2 slice + LN partial sums
      int m = w - 2;
      const float* eb = exch + m * 4 * 256;
      #pragma unroll
      for (int r = 0; r < 4; r++) {
        int ro = (lgp * 4 + r) * 16 + l15;
        float rg = sigm(eb[ro] + cbr1);
        float zg = sigm(eb[256 + ro] + cbz1);
        float ng = tanh_(eb[512 + ro] + bin1 + rg * (eb[768 + ro] + bhn1));
        float hn = (1.f - zg) * ng + zg * h2loc[r];
        h2loc[r] = hn;
        h2c[(m * 16 + lgp * 4 + r) * NH + ucol] = (_Float16)hn;
        float v = hn, v2 = hn * hn;
        v += __shfl_xor(v, 1);  v2 += __shfl_xor(v2, 1);
        v += __shfl_xor(v, 2);  v2 += __shfl_xor(v2, 2);
        v += __shfl_xor(v, 4);  v2 += __shfl_xor(v2, 4);
        v += __shfl_xor(v, 8);  v2 += __shfl_xor(v2, 8);
        if (l15 == 0) {
          float* dp = g_stats + ((cl * BCL + m * 16 + lgp * 4 + r) * BPC + q) * 2;
          dp[0] = v; dp[1] = v2;
        }
      }
    }
    __threadfence();
    __syncthreads();
    if (tid == 0) {  // cluster barrier B (publishes h2(t) + LN partials)
      __hip_atomic_fetch_add(&g_cnt[cl * 2 + 1], 1, __ATOMIC_RELEASE, __HIP_MEMORY_SCOPE_AGENT);
      while (__hip_atomic_load(&g_cnt[cl * 2 + 1], __ATOMIC_ACQUIRE, __HIP_MEMORY_SCOPE_AGENT) <
             BPC * (t + 1))
        __builtin_amdgcn_s_sleep(1);
    }
    __syncthreads();

    if (w >= 2) {  // finish LN stats for this step, accumulate pooling online
      int m = w - 2;
      float s = 0.f, ss = 0.f;
      const float* sp = g_stats + ((cl * BCL + m * 16 + l15) * BPC + lgp * 8) * 2;
      #pragma unroll
      for (int i = 0; i < 8; i++) { s += sp[2 * i]; ss += sp[2 * i + 1]; }
      s += __shfl_xor(s, 16); ss += __shfl_xor(ss, 16);
      s += __shfl_xor(s, 32); ss += __shfl_xor(ss, 32);
      #pragma unroll
      for (int r = 0; r < 4; r++) {
        float S  = __shfl(s,  lgp * 4 + r);
        float SS = __shfl(ss, lgp * 4 + r);
        float mu  = S * (1.f / NH);
        float var = SS * (1.f / NH) - mu * mu;
        float inv = rsqrtf(var + 1e-5f);
        A1[r] += h2loc[r] * inv;
        A0[r] += mu * inv;
        if (t == NT - 1) lastc[r] = (h2loc[r] - mu) * inv;
      }
    }
  }

  if (w >= 2) {  // pooled = LN(h2[T-1]) + mean_t LN(h2[t])  (beta counted in both)
    int m = w - 2;
    float gg = lng[ucol], bb = lnb[ucol];
    #pragma unroll
    for (int r = 0; r < 4; r++) {
      float v = gg * (lastc[r] + (A1[r] - A0[r]) * (1.f / NT)) + 2.f * bb;
      g_pool[(cl * BCL + m * 16 + lgp * 4 + r) * NH + ucol] = v;
    }
  }
}

// pooled @ W_proj.T + b_proj, exact-erf GELU. One block per batch row.
__global__ __launch_bounds__(256) void proj_kernel(const float* __restrict__ bp,
                                                   float* __restrict__ out) {
  __shared__ float pr[NH];
  int b = blockIdx.x, o = threadIdx.x;
  pr[o] = g_pool[b * NH + o];
  pr[o + 256] = g_pool[b * NH + 256 + o];
  __syncthreads();
  float acc = bp[o];
  #pragma unroll 8
  for (int u = 0; u < NH; ++u) acc = fmaf(pr[u], g_Wt[u * 256 + o], acc);
  out[b * 256 + o] = 0.5f * acc * (1.f + erff(acc * 0.70710678118654752f));
}

extern "C" void kernel_launch(void* const* d_in, const int* in_sizes, int n_in,
                              void* d_out, int out_size, void* d_ws, size_t ws_size,
                              hipStream_t stream) {
  const float* x    = (const float*)d_in[0];
  const int*   mask = (const int*)d_in[1];
  const float* Wih0 = (const float*)d_in[2];
  const float* Whh0 = (const float*)d_in[3];
  const float* bih0 = (const float*)d_in[4];
  const float* bhh0 = (const float*)d_in[5];
  const float* Wih1 = (const float*)d_in[6];
  const float* Whh1 = (const float*)d_in[7];
  const float* bih1 = (const float*)d_in[8];
  const float* bhh1 = (const float*)d_in[9];
  const float* lng  = (const float*)d_in[10];
  const float* lnb  = (const float*)d_in[11];
  const float* Wp   = (const float*)d_in[12];
  const float* bp   = (const float*)d_in[13];
  float* out = (float*)d_out;
  (void)in_sizes; (void)n_in; (void)out_size; (void)d_ws; (void)ws_size;

  // Opt in to >64KB dynamic LDS (155648B) for the main kernel.
  hipFuncSetAttribute(reinterpret_cast<const void*>(gru_main),
                      hipFuncAttributeMaxDynamicSharedMemorySize, 155648);

  hipLaunchKernelGGL(init_kernel, dim3(512), dim3(256), 0, stream, Wp);
  hipLaunchKernelGGL(gru_main, dim3(256), dim3(256), 155648, stream,
                     x, mask, Wih0, Whh0, bih0, bhh0, Wih1, Whh1, bih1, bhh1, lng, lnb);
  hipLaunchKernelGGL(proj_kernel, dim3(NB), dim3(256), 0, stream, bp, out);
}

// Round 4
// 9919.078 us; speedup vs baseline: 3.4120x; 3.4120x over previous
//
#include <hip/hip_runtime.h>
#include <math.h>

// Problem constants
#define NB 256   // batch
#define NT 512   // time steps
#define NF 65    // features (x); xm = concat(x, mask) -> 130
#define NH 512   // hidden
#define NCL 8    // clusters == physical XCDs (claimed via HW_REG_XCC_ID)
#define BPC 32   // blocks per cluster (each owns 16 hidden units)
#define BCL 32   // batch rows per cluster

typedef __attribute__((ext_vector_type(8))) _Float16 f16x8;
typedef __attribute__((ext_vector_type(4))) float   f32x4;

// Persistent device scratch. Re-zeroed by init_kernel every launch -> deterministic.
__device__ __align__(16) int      g_claim[NCL];               // per-XCD slot claim
__device__ __align__(16) int      g_flags[2][NCL][BPC];       // cluster barrier flags
__device__ __align__(16) _Float16 g_h1[NCL * 2 * BCL * NH];   // [cl][parity][32][512]
__device__ __align__(16) _Float16 g_h2[NCL * 2 * BCL * NH];
__device__ __align__(16) float    g_stats[NCL * BCL * BPC * 2]; // per-block LN partials
__device__ __align__(16) float    g_pool[NB * NH];
__device__ __align__(16) float    g_Wt[NH * (NH / 2)];          // W_proj transposed

__device__ __forceinline__ float sigm(float v)  { return 1.f / (1.f + __expf(-v)); }
__device__ __forceinline__ float tanh_(float v) { return 1.f - 2.f / (1.f + __expf(2.f * v)); }

// Agent-coherent scalar stores for cross-block-visible data: compiler emits the
// correct gfx950 cache-policy bits (same proven path as the barrier flags).
__device__ __forceinline__ void st_h16(_Float16* p, float v) {
  unsigned short u = __builtin_bit_cast(unsigned short, (_Float16)v);
  __hip_atomic_store((unsigned short*)p, u, __ATOMIC_RELAXED, __HIP_MEMORY_SCOPE_AGENT);
}
__device__ __forceinline__ void st_f32(float* p, float v) {
  __hip_atomic_store(p, v, __ATOMIC_RELAXED, __HIP_MEMORY_SCOPE_AGENT);
}

// 16 coherence-point (sc0 sc1 = system-scope encoding; superset of agent) b128
// loads from one base pointer, offsets 0..960 bytes. Never served from a stale
// CU L1 line. "=&v": dest must not alias the shared addr pair.
#define LDH16(AF, AP)                                                                                \
  asm volatile("global_load_dwordx4 %0, %1, off sc0 sc1"             : "=&v"(AF[0])  : "v"(AP));     \
  asm volatile("global_load_dwordx4 %0, %1, off offset:64 sc0 sc1"   : "=&v"(AF[1])  : "v"(AP));     \
  asm volatile("global_load_dwordx4 %0, %1, off offset:128 sc0 sc1"  : "=&v"(AF[2])  : "v"(AP));     \
  asm volatile("global_load_dwordx4 %0, %1, off offset:192 sc0 sc1"  : "=&v"(AF[3])  : "v"(AP));     \
  asm volatile("global_load_dwordx4 %0, %1, off offset:256 sc0 sc1"  : "=&v"(AF[4])  : "v"(AP));     \
  asm volatile("global_load_dwordx4 %0, %1, off offset:320 sc0 sc1"  : "=&v"(AF[5])  : "v"(AP));     \
  asm volatile("global_load_dwordx4 %0, %1, off offset:384 sc0 sc1"  : "=&v"(AF[6])  : "v"(AP));     \
  asm volatile("global_load_dwordx4 %0, %1, off offset:448 sc0 sc1"  : "=&v"(AF[7])  : "v"(AP));     \
  asm volatile("global_load_dwordx4 %0, %1, off offset:512 sc0 sc1"  : "=&v"(AF[8])  : "v"(AP));     \
  asm volatile("global_load_dwordx4 %0, %1, off offset:576 sc0 sc1"  : "=&v"(AF[9])  : "v"(AP));     \
  asm volatile("global_load_dwordx4 %0, %1, off offset:640 sc0 sc1"  : "=&v"(AF[10]) : "v"(AP));     \
  asm volatile("global_load_dwordx4 %0, %1, off offset:704 sc0 sc1"  : "=&v"(AF[11]) : "v"(AP));     \
  asm volatile("global_load_dwordx4 %0, %1, off offset:768 sc0 sc1"  : "=&v"(AF[12]) : "v"(AP));     \
  asm volatile("global_load_dwordx4 %0, %1, off offset:832 sc0 sc1"  : "=&v"(AF[13]) : "v"(AP));     \
  asm volatile("global_load_dwordx4 %0, %1, off offset:896 sc0 sc1"  : "=&v"(AF[14]) : "v"(AP));     \
  asm volatile("global_load_dwordx4 %0, %1, off offset:960 sc0 sc1"  : "=&v"(AF[15]) : "v"(AP));

#define VM0_FENCE()                                   \
  asm volatile("s_waitcnt vmcnt(0)" ::: "memory");    \
  __builtin_amdgcn_sched_barrier(0);

__global__ void init_kernel(const float* __restrict__ Wp) {
  int i0 = blockIdx.x * blockDim.x + threadIdx.x;
  int n  = gridDim.x * blockDim.x;
  for (int i = i0; i < NCL; i += n) g_claim[i] = 0;
  for (int i = i0; i < 2 * NCL * BPC; i += n) ((int*)g_flags)[i] = 0;
  for (int i = i0; i < NCL * 2 * BCL * NH; i += n) {
    g_h1[i] = (_Float16)0.f;
    g_h2[i] = (_Float16)0.f;
  }
  for (int i = i0; i < NH * (NH / 2); i += n)
    g_Wt[i] = Wp[(i & 255) * NH + (i >> 8)];   // Wt[u][o] = Wp[o][u]
}

// Persistent fused 2-layer GRU + online LayerNorm/pooling.
// grid = 256 blocks (1/CU via 152KB LDS), block = 256 threads (4 waves).
// Clusters are the physical XCDs: all intra-cluster h traffic stays in one L2.
// Cross-block protocol: writer = agent-scope relaxed stores, drained by the
// vmcnt(0) inside __syncthreads, then relaxed agent flag store; reader =
// sc0+sc1 (coherence-point) loads. No fences, no wbl2, no L2 invalidates.
// Wave job map (m = batch M-tile 0/1, g = gate r/z/n):
//   w0: (0,r),(1,z)   w1: (0,z),(1,n)   w2: (0,n) + gate-math m0   w3: (1,r) + gate-math m1
__global__ __launch_bounds__(256, 1) void gru_main(
    const float* __restrict__ x,    const int*   __restrict__ mask,
    const float* __restrict__ Wih0, const float* __restrict__ Whh0,
    const float* __restrict__ bih0, const float* __restrict__ bhh0,
    const float* __restrict__ Wih1, const float* __restrict__ Whh1,
    const float* __restrict__ bih1, const float* __restrict__ bhh1,
    const float* __restrict__ lng,  const float* __restrict__ lnb) {
  extern __shared__ char lds[];
  _Float16* wHH0 = (_Float16*)lds;              // [3][16][64][8] f16 frag-packed, 48KB
  _Float16* wIH1 = (_Float16*)(lds + 49152);
  _Float16* wHH1 = (_Float16*)(lds + 98304);
  float*    exch = (float*)(lds + 147456);      // 8 tiles * 16*16 f32 = 8KB

  const int tid = threadIdx.x;
  const int w = tid >> 6, l = tid & 63, l15 = l & 15, lgp = l >> 4;

  // --- claim a slot in this block's PHYSICAL XCD's cluster ---
  __shared__ int s_cl, s_q;
  if (tid == 0) {
    unsigned xcc;
    asm volatile("s_getreg_b32 %0, hwreg(HW_REG_XCC_ID)" : "=s"(xcc));
    int c = (int)(xcc & 7u);
    int qq = __hip_atomic_fetch_add(&g_claim[c], 1, __ATOMIC_RELAXED,
                                    __HIP_MEMORY_SCOPE_AGENT);
    s_cl = c;
    s_q = qq & 31;
  }
  __syncthreads();
  const int cl = s_cl, q = s_q;
  const int j0 = q * 16;                        // this block's hidden-unit base

  // Pack weight slices into MFMA B-fragment order:
  // B[k][n] = W[g*512 + j0 + n][k]; frag elem (c, lane, j) <-> k = c*32 + (lane>>4)*8 + j, n = lane&15
  for (int e = tid; e < 3 * 16 * NH; e += 256) {
    int k = e & 511, ru = e >> 9;
    int g = ru >> 4, u = ru & 15;
    int src = (g * NH + j0 + u) * NH + k;
    int dst = ((g * 16 + (k >> 5)) * 64 + ((((k >> 3) & 3) << 4) | u)) * 8 + (k & 7);
    wHH0[dst] = (_Float16)Whh0[src];
    wIH1[dst] = (_Float16)Wih1[src];
    wHH1[dst] = (_Float16)Whh1[src];
  }

  int mA = 0, gA = 0, mB = 0, gB = 0; bool two = false;
  if (w == 0)      { mA = 0; gA = 0; mB = 1; gB = 1; two = true; }
  else if (w == 1) { mA = 0; gA = 1; mB = 1; gB = 2; two = true; }
  else if (w == 2) { mA = 0; gA = 2; }
  else             { mA = 1; gA = 0; }

  // W_ih0 slice fragments in registers (K=130 padded to 160)
  f16x8 wfA[5], wfB[5];
  #pragma unroll
  for (int c = 0; c < 5; c++) {
    #pragma unroll
    for (int j = 0; j < 8; j++) {
      int k = c * 32 + (lgp << 3) + j;
      float v1 = (k < 130) ? Wih0[(gA * NH + j0 + l15) * 130 + k] : 0.f;
      wfA[c][j] = (_Float16)v1;
      float v2 = (two && k < 130) ? Wih0[(gB * NH + j0 + l15) * 130 + k] : 0.f;
      wfB[c][j] = (_Float16)v2;
    }
  }

  // Gate-math wave persistent state
  const int ucol = j0 + l15;
  float cbr0 = 0, cbz0 = 0, bin0 = 0, bhn0 = 0, cbr1 = 0, cbz1 = 0, bin1 = 0, bhn1 = 0;
  if (w >= 2) {
    cbr0 = bih0[ucol] + bhh0[ucol];
    cbz0 = bih0[NH + ucol] + bhh0[NH + ucol];
    bin0 = bih0[2 * NH + ucol];
    bhn0 = bhh0[2 * NH + ucol];
    cbr1 = bih1[ucol] + bhh1[ucol];
    cbz1 = bih1[NH + ucol] + bhh1[NH + ucol];
    bin1 = bih1[2 * NH + ucol];
    bhn1 = bhh1[2 * NH + ucol];
  }
  float h1loc[4] = {0, 0, 0, 0}, h2loc[4] = {0, 0, 0, 0};
  float A1[4] = {0, 0, 0, 0}, A0[4] = {0, 0, 0, 0}, lastc[4] = {0, 0, 0, 0};

  // K=512 GEMM, A read at the coherence point, 2-acc K-split for MFMA ILP.
  auto gemm512 = [&](const _Float16* A, int m, const _Float16* Bf) -> f32x4 {
    const _Float16* ap = A + (m * 16 + l15) * NH + (lgp << 3);
    f16x8 af[16];
    LDH16(af, ap);
    VM0_FENCE();
    f32x4 a0 = {0.f, 0.f, 0.f, 0.f}, a1 = {0.f, 0.f, 0.f, 0.f};
    #pragma unroll
    for (int c = 0; c < 8; c++) {
      f16x8 b0 = *(const f16x8*)(Bf + ((2 * c) * 64 + l) * 8);
      f16x8 b1 = *(const f16x8*)(Bf + ((2 * c + 1) * 64 + l) * 8);
      a0 = __builtin_amdgcn_mfma_f32_16x16x32_f16(af[2 * c], b0, a0, 0, 0, 0);
      a1 = __builtin_amdgcn_mfma_f32_16x16x32_f16(af[2 * c + 1], b1, a1, 0, 0, 0);
    }
    return a0 + a1;
  };

  // Fused pair of K=512 GEMMs (32 loads in flight under one waitcnt).
  auto gemm2 = [&](const _Float16* A1p, const _Float16* A2p, int m,
                   const _Float16* B1, const _Float16* B2, f32x4& r1, f32x4& r2) {
    const _Float16* ap = A1p + (m * 16 + l15) * NH + (lgp << 3);
    const _Float16* aq = A2p + (m * 16 + l15) * NH + (lgp << 3);
    f16x8 af[16], ag[16];
    LDH16(af, ap);
    LDH16(ag, aq);
    VM0_FENCE();
    f32x4 a0 = {0.f, 0.f, 0.f, 0.f}, a1 = {0.f, 0.f, 0.f, 0.f};
    f32x4 b0 = {0.f, 0.f, 0.f, 0.f}, b1 = {0.f, 0.f, 0.f, 0.f};
    #pragma unroll
    for (int c = 0; c < 8; c++) {
      f16x8 u0 = *(const f16x8*)(B1 + ((2 * c) * 64 + l) * 8);
      f16x8 u1 = *(const f16x8*)(B1 + ((2 * c + 1) * 64 + l) * 8);
      f16x8 v0 = *(const f16x8*)(B2 + ((2 * c) * 64 + l) * 8);
      f16x8 v1 = *(const f16x8*)(B2 + ((2 * c + 1) * 64 + l) * 8);
      a0 = __builtin_amdgcn_mfma_f32_16x16x32_f16(af[2 * c], u0, a0, 0, 0, 0);
      b0 = __builtin_amdgcn_mfma_f32_16x16x32_f16(ag[2 * c], v0, b0, 0, 0, 0);
      a1 = __builtin_amdgcn_mfma_f32_16x16x32_f16(af[2 * c + 1], u1, a1, 0, 0, 0);
      b1 = __builtin_amdgcn_mfma_f32_16x16x32_f16(ag[2 * c + 1], v1, b1, 0, 0, 0);
    }
    r1 = a0 + a1;
    r2 = b0 + b1;
  };

  // Layer-0 input projection: A = concat(x, mask)[t] built on the fly (immutable
  // inputs -> plain cached loads are fine).
  auto gemmih0 = [&](int m, const f16x8* wf, int t) -> f32x4 {
    int b = cl * BCL + m * 16 + l15;
    const float* xb = x + ((long)b * NT + t) * NF;
    const int*   mb = mask + ((long)b * NT + t) * NF;
    f32x4 acc = {0.f, 0.f, 0.f, 0.f};
    #pragma unroll
    for (int c = 0; c < 5; c++) {
      f16x8 av;
      #pragma unroll
      for (int j = 0; j < 8; j++) {
        int k = c * 32 + (lgp << 3) + j;
        float v = 0.f;
        if (k < NF) v = xb[k];
        else if (k < 2 * NF) v = (float)mb[k - NF];
        av[j] = (_Float16)v;
      }
      acc = __builtin_amdgcn_mfma_f32_16x16x32_f16(av, wf[c], acc, 0, 0, 0);
    }
    return acc;
  };

  auto storeTile = [&](int slot, f32x4 a) {
    float* et = exch + slot * 256;
    #pragma unroll
    for (int r = 0; r < 4; r++) et[(lgp * 4 + r) * 16 + l15] = a[r];
  };

  // Cluster barrier. Writer release = vmcnt(0)-drained agent stores (inside the
  // preceding __syncthreads) + relaxed agent flag store. Reader side = sc0 sc1
  // loads for all cross-block data.
  auto clusterBarrier = [&](int ph, int t) {
    if (tid == 0)
      __hip_atomic_store(&g_flags[ph][cl][q], t + 1, __ATOMIC_RELAXED,
                         __HIP_MEMORY_SCOPE_AGENT);
    if (w == 0) {
      for (;;) {
        int v = (l < BPC)
                    ? __hip_atomic_load(&g_flags[ph][cl][l], __ATOMIC_RELAXED,
                                        __HIP_MEMORY_SCOPE_AGENT)
                    : (t + 1);
        if (__all(v >= t + 1)) break;
        __builtin_amdgcn_s_sleep(1);
      }
    }
    __syncthreads();
  };

  __syncthreads();

  for (int t = 0; t < NT; ++t) {
    const _Float16* h1p = g_h1 + (cl * 2 + ((t + 1) & 1)) * BCL * NH;
    _Float16*       h1c = g_h1 + (cl * 2 + (t & 1)) * BCL * NH;
    const _Float16* h2p = g_h2 + (cl * 2 + ((t + 1) & 1)) * BCL * NH;
    _Float16*       h2c = g_h2 + (cl * 2 + (t & 1)) * BCL * NH;

    // ---- phase A: layer-0 gates ----
    {
      f32x4 ai = gemmih0(mA, wfA, t);
      f32x4 ah = gemm512(h1p, mA, wHH0 + (gA < 2 ? gA : 2) * 8192);
      if (gA < 2) storeTile(mA * 4 + gA, ai + ah);
      else        { storeTile(mA * 4 + 2, ai); storeTile(mA * 4 + 3, ah); }
    }
    if (two) {
      f32x4 ai = gemmih0(mB, wfB, t);
      f32x4 ah = gemm512(h1p, mB, wHH0 + (gB < 2 ? gB : 2) * 8192);
      if (gB < 2) storeTile(mB * 4 + gB, ai + ah);
      else        { storeTile(mB * 4 + 2, ai); storeTile(mB * 4 + 3, ah); }
    }
    __syncthreads();

    if (w >= 2) {  // gate math layer 0, update h1 slice
      int m = w - 2;
      const float* eb = exch + m * 4 * 256;
      #pragma unroll
      for (int r = 0; r < 4; r++) {
        int ro = (lgp * 4 + r) * 16 + l15;
        float rg = sigm(eb[ro] + cbr0);
        float zg = sigm(eb[256 + ro] + cbz0);
        float ng = tanh_(eb[512 + ro] + bin0 + rg * (eb[768 + ro] + bhn0));
        float hn = (1.f - zg) * ng + zg * h1loc[r];
        h1loc[r] = hn;
        st_h16(&h1c[(m * 16 + lgp * 4 + r) * NH + ucol], hn);
      }
    }
    __syncthreads();           // drains h1 stores to (shared) L2
    clusterBarrier(0, t);      // publishes h1(t) cluster-wide

    // ---- phase B: layer-1 gates ----
    {
      f32x4 r1, r2;
      gemm2(h1c, h2p, mA, wIH1 + (gA < 2 ? gA : 2) * 8192,
            wHH1 + (gA < 2 ? gA : 2) * 8192, r1, r2);
      if (gA < 2) storeTile(mA * 4 + gA, r1 + r2);
      else        { storeTile(mA * 4 + 2, r1); storeTile(mA * 4 + 3, r2); }
    }
    if (two) {
      f32x4 r1, r2;
      gemm2(h1c, h2p, mB, wIH1 + (gB < 2 ? gB : 2) * 8192,
            wHH1 + (gB < 2 ? gB : 2) * 8192, r1, r2);
      if (gB < 2) storeTile(mB * 4 + gB, r1 + r2);
      else        { storeTile(mB * 4 + 2, r1); storeTile(mB * 4 + 3, r2); }
    }
    __syncthreads();

    if (w >= 2) {  // gate math layer 1, update h2 slice + LN partial sums
      int m = w - 2;
      const float* eb = exch + m * 4 * 256;
      #pragma unroll
      for (int r = 0; r < 4; r++) {
        int ro = (lgp * 4 + r) * 16 + l15;
        float rg = sigm(eb[ro] + cbr1);
        float zg = sigm(eb[256 + ro] + cbz1);
        float ng = tanh_(eb[512 + ro] + bin1 + rg * (eb[768 + ro] + bhn1));
        float hn = (1.f - zg) * ng + zg * h2loc[r];
        h2loc[r] = hn;
        st_h16(&h2c[(m * 16 + lgp * 4 + r) * NH + ucol], hn);
        float v = hn, v2 = hn * hn;
        v += __shfl_xor(v, 1);  v2 += __shfl_xor(v2, 1);
        v += __shfl_xor(v, 2);  v2 += __shfl_xor(v2, 2);
        v += __shfl_xor(v, 4);  v2 += __shfl_xor(v2, 4);
        v += __shfl_xor(v, 8);  v2 += __shfl_xor(v2, 8);
        if (l15 == 0) {
          float* dp = g_stats + ((cl * BCL + m * 16 + lgp * 4 + r) * BPC + q) * 2;
          st_f32(&dp[0], v); st_f32(&dp[1], v2);
        }
      }
    }
    __syncthreads();           // drains h2 + stats stores to L2
    clusterBarrier(1, t);      // publishes h2(t) + LN partials cluster-wide

    if (w >= 2) {  // finish LN stats for this step, accumulate pooling online
      int m = w - 2;
      const float* sp = g_stats + ((cl * BCL + m * 16 + l15) * BPC + lgp * 8) * 2;
      f32x4 st0, st1, st2, st3;   // 16 floats = 8 (sum,sumsq) pairs, L2-coherent
      asm volatile("global_load_dwordx4 %0, %1, off sc0 sc1"           : "=&v"(st0) : "v"(sp));
      asm volatile("global_load_dwordx4 %0, %1, off offset:16 sc0 sc1" : "=&v"(st1) : "v"(sp));
      asm volatile("global_load_dwordx4 %0, %1, off offset:32 sc0 sc1" : "=&v"(st2) : "v"(sp));
      asm volatile("global_load_dwordx4 %0, %1, off offset:48 sc0 sc1" : "=&v"(st3) : "v"(sp));
      VM0_FENCE();
      float s  = (st0[0] + st1[0]) + (st2[0] + st3[0]) + (st0[2] + st1[2]) + (st2[2] + st3[2]);
      float ss = (st0[1] + st1[1]) + (st2[1] + st3[1]) + (st0[3] + st1[3]) + (st2[3] + st3[3]);
      s += __shfl_xor(s, 16); ss += __shfl_xor(ss, 16);
      s += __shfl_xor(s, 32); ss += __shfl_xor(ss, 32);
      #pragma unroll
      for (int r = 0; r < 4; r++) {
        float S  = __shfl(s,  lgp * 4 + r);
        float SS = __shfl(ss, lgp * 4 + r);
        float mu  = S * (1.f / NH);
        float var = SS * (1.f / NH) - mu * mu;
        float inv = rsqrtf(var + 1e-5f);
        A1[r] += h2loc[r] * inv;
        A0[r] += mu * inv;
        if (t == NT - 1) lastc[r] = (h2loc[r] - mu) * inv;
      }
    }
  }

  if (w >= 2) {  // pooled = LN(h2[T-1]) + mean_t LN(h2[t])  (beta counted in both)
    int m = w - 2;
    float gg = lng[ucol], bb = lnb[ucol];
    #pragma unroll
    for (int r = 0; r < 4; r++) {
      float v = gg * (lastc[r] + (A1[r] - A0[r]) * (1.f / NT)) + 2.f * bb;
      g_pool[(cl * BCL + m * 16 + lgp * 4 + r) * NH + ucol] = v;
    }
  }
}

// pooled @ W_proj.T + b_proj, exact-erf GELU. One block per batch row.
// (g_pool visibility across the kernel boundary is guaranteed by HIP's
// end-of-kernel release / start-of-kernel acquire on the same stream.)
__global__ __launch_bounds__(256) void proj_kernel(const float* __restrict__ bp,
                                                   float* __restrict__ out) {
  __shared__ float pr[NH];
  int b = blockIdx.x, o = threadIdx.x;
  pr[o] = g_pool[b * NH + o];
  pr[o + 256] = g_pool[b * NH + 256 + o];
  __syncthreads();
  float acc = bp[o];
  #pragma unroll 8
  for (int u = 0; u < NH; ++u) acc = fmaf(pr[u], g_Wt[u * 256 + o], acc);
  out[b * 256 + o] = 0.5f * acc * (1.f + erff(acc * 0.70710678118654752f));
}

extern "C" void kernel_launch(void* const* d_in, const int* in_sizes, int n_in,
                              void* d_out, int out_size, void* d_ws, size_t ws_size,
                              hipStream_t stream) {
  const float* x    = (const float*)d_in[0];
  const int*   mask = (const int*)d_in[1];
  const float* Wih0 = (const float*)d_in[2];
  const float* Whh0 = (const float*)d_in[3];
  const float* bih0 = (const float*)d_in[4];
  const float* bhh0 = (const float*)d_in[5];
  const float* Wih1 = (const float*)d_in[6];
  const float* Whh1 = (const float*)d_in[7];
  const float* bih1 = (const float*)d_in[8];
  const float* bhh1 = (const float*)d_in[9];
  const float* lng  = (const float*)d_in[10];
  const float* lnb  = (const float*)d_in[11];
  const float* Wp   = (const float*)d_in[12];
  const float* bp   = (const float*)d_in[13];
  float* out = (float*)d_out;
  (void)in_sizes; (void)n_in; (void)out_size; (void)d_ws; (void)ws_size;

  // Opt in to >64KB dynamic LDS (155648B) for the main kernel.
  hipFuncSetAttribute(reinterpret_cast<const void*>(gru_main),
                      hipFuncAttributeMaxDynamicSharedMemorySize, 155648);

  hipLaunchKernelGGL(init_kernel, dim3(512), dim3(256), 0, stream, Wp);
  hipLaunchKernelGGL(gru_main, dim3(256), dim3(256), 155648, stream,
                     x, mask, Wih0, Whh0, bih0, bhh0, Wih1, Whh1, bih1, bhh1, lng, lnb);
  hipLaunchKernelGGL(proj_kernel, dim3(NB), dim3(256), 0, stream, bp, out);
}

// Round 5
// 5468.678 us; speedup vs baseline: 6.1887x; 1.8138x over previous
//
#include <hip/hip_runtime.h>
#include <math.h>

#define NB 256   // batch
#define NT 512   // time steps
#define NF 65    // features
#define NH 512   // hidden
#define NCL 8    // clusters == physical XCDs
#define BPC 32   // blocks per cluster
#define BCL 32   // batch rows per cluster
#define XMS 136  // padded xm row stride (f16 elems), 17*8 -> 16B-aligned rows

typedef __attribute__((ext_vector_type(8))) _Float16 f16x8;
typedef __attribute__((ext_vector_type(4))) float   f32x4;

__device__ __align__(16) int      g_claim[NCL];
__device__ __align__(16) int      g_flags[2][NCL][BPC];
__device__ __align__(16) _Float16 g_h1[NCL*2*BCL*NH];
__device__ __align__(16) _Float16 g_h2[NCL*2*BCL*NH];
__device__ __align__(16) float    g_stats[NCL*BCL*BPC*2];
__device__ __align__(16) float    g_pool[NB*NH];
__device__ __align__(16) float    g_Wt[NH*(NH/2)];
__device__ __align__(16) _Float16 g_xm[(size_t)NB*NT*XMS + 256];  // concat(x,mask) in f16

__device__ __forceinline__ float sigm(float v)  { return 1.f/(1.f+__expf(-v)); }
__device__ __forceinline__ float tanh_(float v) { return 1.f-2.f/(1.f+__expf(2.f*v)); }

// PROVEN (round 4) coherence pair: agent-scope atomic stores + sc0 sc1 loads.
__device__ __forceinline__ void st_h16(_Float16* p, float v) {
  unsigned short u = __builtin_bit_cast(unsigned short, (_Float16)v);
  __hip_atomic_store((unsigned short*)p, u, __ATOMIC_RELAXED, __HIP_MEMORY_SCOPE_AGENT);
}
__device__ __forceinline__ void st_f32(float* p, float v) {
  __hip_atomic_store(p, v, __ATOMIC_RELAXED, __HIP_MEMORY_SCOPE_AGENT);
}

#define GLDC(D,P,O) asm volatile("global_load_dwordx4 %0, %1, off offset:" #O " sc0 sc1" : "=&v"(D) : "v"(P));
#define GLDP(D,P,O) asm volatile("global_load_dwordx4 %0, %1, off offset:" #O : "=&v"(D) : "v"(P));
#define LDH16(AF,AP)                                                        \
  GLDC(AF[0],AP,0)    GLDC(AF[1],AP,64)   GLDC(AF[2],AP,128)  GLDC(AF[3],AP,192)  \
  GLDC(AF[4],AP,256)  GLDC(AF[5],AP,320)  GLDC(AF[6],AP,384)  GLDC(AF[7],AP,448)  \
  GLDC(AF[8],AP,512)  GLDC(AF[9],AP,576)  GLDC(AF[10],AP,640) GLDC(AF[11],AP,704) \
  GLDC(AF[12],AP,768) GLDC(AF[13],AP,832) GLDC(AF[14],AP,896) GLDC(AF[15],AP,960)
#define LDH8(AF,AP)                                                         \
  GLDC(AF[0],AP,0)    GLDC(AF[1],AP,64)   GLDC(AF[2],AP,128)  GLDC(AF[3],AP,192)  \
  GLDC(AF[4],AP,256)  GLDC(AF[5],AP,320)  GLDC(AF[6],AP,384)  GLDC(AF[7],AP,448)
#define VMF(N)                                          \
  asm volatile("s_waitcnt vmcnt(" #N ")" ::: "memory"); \
  __builtin_amdgcn_sched_barrier(0);
#define MF(a,b,c) __builtin_amdgcn_mfma_f32_16x16x32_f16(a,b,c,0,0,0)
#define BF(W,g,c) (*(const f16x8*)((W) + (((g)*16+(c))*64 + l)*8))

__global__ void init_kernel(const float* __restrict__ Wp,
                            const float* __restrict__ x, const int* __restrict__ mask) {
  long i0 = (long)blockIdx.x * blockDim.x + threadIdx.x;
  long n  = (long)gridDim.x * blockDim.x;
  for (long i = i0; i < NCL; i += n) g_claim[i] = 0;
  for (long i = i0; i < 2*NCL*BPC; i += n) ((int*)g_flags)[i] = 0;
  for (long i = i0; i < NCL*2*BCL*NH; i += n) { g_h1[i]=(_Float16)0.f; g_h2[i]=(_Float16)0.f; }
  for (long i = i0; i < NH*(NH/2); i += n) g_Wt[i] = Wp[(i & 255)*NH + (i >> 8)];
  const long total = (long)NB*NT*XMS;
  for (long i = i0; i < total + 256; i += n) {
    if (i >= total) { g_xm[i] = (_Float16)0.f; continue; }
    long row = i / XMS; int col = (int)(i % XMS);
    float v = 0.f;
    if (col < NF)          v = x[row*NF + col];
    else if (col < 2*NF)   v = (float)mask[row*NF + col - NF];
    g_xm[i] = (_Float16)v;
  }
}

// Persistent fused 2-layer GRU. 256 blocks (1/CU), 256 threads (4 waves).
// Wave roles: p = w>>1 (batch m-tile), hf = w&1.
//   phase A: K-split (hf) over h1(t-1), 3 gates each; ih0 gates r,n on hf0 / z on hf1.
//   phase B: input-split: hf0 = ih1 (h1c fresh, 1 exposed fence), hf1 = hh1 (h2p prefetched).
//   hf0 waves (w0,w2) do gate math + LN stats; w1 polls cluster barriers.
// Register carry: phase B's h1c loads ARE next phase A's operand (no reload).
__global__ __launch_bounds__(256, 1) void gru_main(
    const float* __restrict__ Wih0, const float* __restrict__ Whh0,
    const float* __restrict__ bih0, const float* __restrict__ bhh0,
    const float* __restrict__ Wih1, const float* __restrict__ Whh1,
    const float* __restrict__ bih1, const float* __restrict__ bhh1,
    const float* __restrict__ lng,  const float* __restrict__ lnb) {
  extern __shared__ char lds[];
  _Float16* wHH0 = (_Float16*)lds;
  _Float16* wIH1 = (_Float16*)(lds + 49152);
  _Float16* wHH1 = (_Float16*)(lds + 98304);
  float*    exch = (float*)(lds + 147456);   // 14 tiles * 1KB

  const int tid = threadIdx.x;
  const int w = tid >> 6, l = tid & 63, l15 = l & 15, lgp = l >> 4;
  const int p = w >> 1, hf = w & 1;

  if (tid == 0) {
    unsigned xcc;
    asm volatile("s_getreg_b32 %0, hwreg(HW_REG_XCC_ID)" : "=s"(xcc));
    int c = (int)(xcc & 7u);
    int qq = __hip_atomic_fetch_add(&g_claim[c], 1, __ATOMIC_RELAXED, __HIP_MEMORY_SCOPE_AGENT);
    ((int*)exch)[0] = c; ((int*)exch)[1] = qq & 31;
  }
  __syncthreads();
  const int cl = ((int*)exch)[0], q = ((int*)exch)[1];
  const int j0 = q * 16;

  // Pack weight slices into MFMA B-fragment order (as r4).
  for (int e = tid; e < 3*16*NH; e += 256) {
    int k = e & 511, ru = e >> 9;
    int g = ru >> 4, u = ru & 15;
    int src = (g*NH + j0 + u)*NH + k;
    int dst = ((g*16 + (k>>5))*64 + ((((k>>3)&3)<<4) | u))*8 + (k&7);
    wHH0[dst] = (_Float16)Whh0[src];
    wIH1[dst] = (_Float16)Wih1[src];
    wHH1[dst] = (_Float16)Whh1[src];
  }

  // W_ih0 frags: hf0 -> [0..4]=gate r, [5..9]=gate n ; hf1 -> [0..4]=gate z
  f16x8 wfA[10];
  #pragma unroll
  for (int c = 0; c < 5; c++) {
    #pragma unroll
    for (int j = 0; j < 8; j++) {
      int k = c*32 + lgp*8 + j;
      float v0 = (k < 130) ? Wih0[((hf ? 1 : 0)*NH + j0 + l15)*130 + k] : 0.f;
      wfA[c][j] = (_Float16)v0;
      float v1 = (!hf && k < 130) ? Wih0[(2*NH + j0 + l15)*130 + k] : 0.f;
      wfA[5+c][j] = (_Float16)v1;
    }
  }

  const int ucol = j0 + l15;
  const float cbr0 = bih0[ucol] + bhh0[ucol];
  const float cbz0 = bih0[NH+ucol] + bhh0[NH+ucol];
  const float bin0 = bih0[2*NH+ucol], bhn0 = bhh0[2*NH+ucol];
  const float cbr1 = bih1[ucol] + bhh1[ucol];
  const float cbz1 = bih1[NH+ucol] + bhh1[NH+ucol];
  const float bin1 = bih1[2*NH+ucol], bhn1 = bhh1[2*NH+ucol];

  const int arow0 = (p*16 + l15)*NH + lgp*8;
  const _Float16* xptr = g_xm + ((long)(cl*BCL + p*16 + l15)*NT)*XMS + lgp*8;
  const float* spL = g_stats + ((cl*BCL + p*16 + l15)*BPC + lgp*8)*2;

  float h1loc[4]={0,0,0,0}, h2loc[4]={0,0,0,0};
  float A1[4]={0,0,0,0}, A0[4]={0,0,0,0}, lastc[4]={0,0,0,0};
  f16x8 af1[16], af2[16], pre[8], xmf[5];
  f32x4 sts0, sts1, sts2, sts3;
  const f32x4 z4v = {0.f,0.f,0.f,0.f};

  auto stTile = [&](int idx, f32x4 a) {
    float* et = exch + idx*256;
    #pragma unroll
    for (int r = 0; r < 4; r++) et[(lgp*4+r)*16 + l15] = a[r];
  };
  auto lnFinish = [&](bool last) {
    float s  = (sts0[0]+sts1[0]) + (sts2[0]+sts3[0]) + (sts0[2]+sts1[2]) + (sts2[2]+sts3[2]);
    float ss = (sts0[1]+sts1[1]) + (sts2[1]+sts3[1]) + (sts0[3]+sts1[3]) + (sts2[3]+sts3[3]);
    s += __shfl_xor(s,16); ss += __shfl_xor(ss,16);
    s += __shfl_xor(s,32); ss += __shfl_xor(ss,32);
    #pragma unroll
    for (int r = 0; r < 4; r++) {
      float S = __shfl(s, lgp*4+r), SS = __shfl(ss, lgp*4+r);
      float mu = S*(1.f/NH), var = SS*(1.f/NH) - mu*mu;
      float inv = rsqrtf(var + 1e-5f);
      A1[r] += h2loc[r]*inv; A0[r] += mu*inv;
      if (last) lastc[r] = (h2loc[r]-mu)*inv;
    }
  };
  auto clusterBarrier = [&](int ph, int t) {
    if (tid == 0)
      __hip_atomic_store(&g_flags[ph][cl][q], t+1, __ATOMIC_RELAXED, __HIP_MEMORY_SCOPE_AGENT);
    if (w == 1) {
      const int* fp = &g_flags[ph][cl][0];
      for (;;) {
        int v = (l < BPC) ? __hip_atomic_load(&fp[l], __ATOMIC_RELAXED, __HIP_MEMORY_SCOPE_AGENT)
                          : (t+1);
        if (__all(v >= t+1)) break;
        __builtin_amdgcn_s_sleep(1);
      }
    }
    __syncthreads();
  };

  // Prologue: h1(-1)=0 halves + xm(0); fence once.
  {
    const _Float16* h1p0 = g_h1 + (cl*2 + 1)*BCL*NH;
    if (hf == 0) { const _Float16* ap = h1p0 + arow0;        LDH8(af1, ap) }
    else         { const _Float16* ap = h1p0 + arow0 + 256;  LDH8(pre, ap) }
    GLDP(xmf[0],xptr,0) GLDP(xmf[1],xptr,64) GLDP(xmf[2],xptr,128)
    GLDP(xmf[3],xptr,192) GLDP(xmf[4],xptr,256)
    VMF(0)
  }
  __syncthreads();   // weight pack visible

  for (int t = 0; t < NT; ++t) {
    const _Float16* h1c = g_h1 + (cl*2 + (t&1))*BCL*NH;
    const _Float16* h2p = g_h2 + (cl*2 + ((t+1)&1))*BCL*NH;
    _Float16*       h2c = g_h2 + (cl*2 + (t&1))*BCL*NH;
    _Float16*       h1w = (_Float16*)h1c;

    // step top: prefetch issues (consumed later; drained by intervening syncs)
    if (hf) { const _Float16* ap = h2p + arow0; LDH16(af2, ap) }
    else if (t > 0) {
      GLDC(sts0,spL,0) GLDC(sts1,spL,16) GLDC(sts2,spL,32) GLDC(sts3,spL,48)
    }

    // ---- phase A: all operands already in registers/LDS ----
    f32x4 aRa=z4v,aRb=z4v,aZa=z4v,aZb=z4v,aNa=z4v,aNb=z4v,aNI=z4v;
    if (hf == 0) {
      #pragma unroll
      for (int cc = 0; cc < 4; cc++) {
        aRa = MF(af1[2*cc],  BF(wHH0,0,2*cc),  aRa); aRb = MF(af1[2*cc+1],BF(wHH0,0,2*cc+1),aRb);
        aZa = MF(af1[2*cc],  BF(wHH0,1,2*cc),  aZa); aZb = MF(af1[2*cc+1],BF(wHH0,1,2*cc+1),aZb);
        aNa = MF(af1[2*cc],  BF(wHH0,2,2*cc),  aNa); aNb = MF(af1[2*cc+1],BF(wHH0,2,2*cc+1),aNb);
      }
      #pragma unroll
      for (int c = 0; c < 5; c++) {
        aRa = MF(xmf[c], wfA[c],   aRa);
        aNI = MF(xmf[c], wfA[5+c], aNI);
      }
    } else {
      #pragma unroll
      for (int cc = 0; cc < 4; cc++) {
        aRa = MF(pre[2*cc],  BF(wHH0,0,8+2*cc),  aRa); aRb = MF(pre[2*cc+1],BF(wHH0,0,9+2*cc),aRb);
        aZa = MF(pre[2*cc],  BF(wHH0,1,8+2*cc),  aZa); aZb = MF(pre[2*cc+1],BF(wHH0,1,9+2*cc),aZb);
        aNa = MF(pre[2*cc],  BF(wHH0,2,8+2*cc),  aNa); aNb = MF(pre[2*cc+1],BF(wHH0,2,9+2*cc),aNb);
      }
      #pragma unroll
      for (int c = 0; c < 5; c++) aZa = MF(xmf[c], wfA[c], aZa);
    }
    // slots per p: [0]=R0 [1]=R1 [2]=Z0 [3]=Z1 [4]=NH0 [5]=NH1 [6]=NI
    stTile(p*7 + hf,     aRa + aRb);
    stTile(p*7 + 2 + hf, aZa + aZb);
    stTile(p*7 + 4 + hf, aNa + aNb);
    if (hf == 0) { stTile(p*7 + 6, aNI); VMF(0) if (t > 0) lnFinish(false); }
    __syncthreads();

    if (hf == 0) {  // gate math layer 0
      const float* eb = exch + p*7*256;
      #pragma unroll
      for (int r = 0; r < 4; r++) {
        int ro = (lgp*4+r)*16 + l15;
        float rg = sigm(eb[ro] + eb[256+ro] + cbr0);
        float zg = sigm(eb[512+ro] + eb[768+ro] + cbz0);
        float ng = tanh_(eb[1536+ro] + bin0 + rg*(eb[1024+ro] + eb[1280+ro] + bhn0));
        float hn = (1.f-zg)*ng + zg*h1loc[r];
        h1loc[r] = hn;
        st_h16(&h1w[(p*16 + lgp*4 + r)*NH + ucol], hn);
      }
    }
    __syncthreads();          // drains h1 stores (agent) to MALL
    clusterBarrier(0, t);     // publishes h1(t)

    // ---- phase B ----
    f32x4 bRa=z4v,bRb=z4v,bZa=z4v,bZb=z4v,bNa=z4v,bNb=z4v;
    if (hf == 0) {
      const _Float16* ap = h1c + arow0;
      LDH16(af1, ap)                     // fresh h1(t); also next phase A's half0
      xptr += XMS;                       // xm(t+1) prefetch rides the same fence window
      GLDP(xmf[0],xptr,0) GLDP(xmf[1],xptr,64) GLDP(xmf[2],xptr,128)
      GLDP(xmf[3],xptr,192) GLDP(xmf[4],xptr,256)
      VMF(0)
      #pragma unroll
      for (int cc = 0; cc < 8; cc++) {
        bRa = MF(af1[2*cc],  BF(wIH1,0,2*cc),  bRa); bRb = MF(af1[2*cc+1],BF(wIH1,0,2*cc+1),bRb);
        bZa = MF(af1[2*cc],  BF(wIH1,1,2*cc),  bZa); bZb = MF(af1[2*cc+1],BF(wIH1,1,2*cc+1),bZb);
        bNa = MF(af1[2*cc],  BF(wIH1,2,2*cc),  bNa); bNb = MF(af1[2*cc+1],BF(wIH1,2,2*cc+1),bNb);
      }
      // slots per p: [0]=Ri [1]=Rh [2]=Zi [3]=Zh [4]=Ni [5]=Nh
      stTile(p*7+0, bRa+bRb); stTile(p*7+2, bZa+bZb); stTile(p*7+4, bNa+bNb);
    } else {
      const _Float16* ap = h1c + arow0 + 256;
      LDH8(pre, ap)                      // next phase A's half1 (no fence needed now)
      xptr += XMS;
      GLDP(xmf[0],xptr,0) GLDP(xmf[1],xptr,64) GLDP(xmf[2],xptr,128)
      GLDP(xmf[3],xptr,192) GLDP(xmf[4],xptr,256)
      // af2 (h2p) prefetched at step top -> compute immediately
      #pragma unroll
      for (int cc = 0; cc < 8; cc++) {
        bRa = MF(af2[2*cc],  BF(wHH1,0,2*cc),  bRa); bRb = MF(af2[2*cc+1],BF(wHH1,0,2*cc+1),bRb);
        bZa = MF(af2[2*cc],  BF(wHH1,1,2*cc),  bZa); bZb = MF(af2[2*cc+1],BF(wHH1,1,2*cc+1),bZb);
        bNa = MF(af2[2*cc],  BF(wHH1,2,2*cc),  bNa); bNb = MF(af2[2*cc+1],BF(wHH1,2,2*cc+1),bNb);
      }
      stTile(p*7+1, bRa+bRb); stTile(p*7+3, bZa+bZb); stTile(p*7+5, bNa+bNb);
    }
    __syncthreads();

    if (hf == 0) {  // gate math layer 1 + LN partials
      const float* eb = exch + p*7*256;
      #pragma unroll
      for (int r = 0; r < 4; r++) {
        int ro = (lgp*4+r)*16 + l15;
        float rg = sigm(eb[ro] + eb[256+ro] + cbr1);
        float zg = sigm(eb[512+ro] + eb[768+ro] + cbz1);
        float ng = tanh_(eb[1024+ro] + bin1 + rg*(eb[1280+ro] + bhn1));
        float hn = (1.f-zg)*ng + zg*h2loc[r];
        h2loc[r] = hn;
        st_h16(&h2c[(p*16 + lgp*4 + r)*NH + ucol], hn);
        float v = hn, v2 = hn*hn;
        v += __shfl_xor(v,1); v2 += __shfl_xor(v2,1);
        v += __shfl_xor(v,2); v2 += __shfl_xor(v2,2);
        v += __shfl_xor(v,4); v2 += __shfl_xor(v2,4);
        v += __shfl_xor(v,8); v2 += __shfl_xor(v2,8);
        if (l15 == 0) {
          float* dp = g_stats + ((cl*BCL + p*16 + lgp*4 + r)*BPC + q)*2;
          st_f32(&dp[0], v); st_f32(&dp[1], v2);
        }
      }
    }
    __syncthreads();          // drains h2 + stats
    clusterBarrier(1, t);     // publishes h2(t) + LN partials
  }

  if (hf == 0) {  // final LN (t=NT-1) + pooled write
    GLDC(sts0,spL,0) GLDC(sts1,spL,16) GLDC(sts2,spL,32) GLDC(sts3,spL,48)
    VMF(0)
    lnFinish(true);
    float gg = lng[ucol], bb = lnb[ucol];
    #pragma unroll
    for (int r = 0; r < 4; r++) {
      float v = gg*(lastc[r] + (A1[r]-A0[r])*(1.f/NT)) + 2.f*bb;
      g_pool[(cl*BCL + p*16 + lgp*4 + r)*NH + ucol] = v;
    }
  }
}

__global__ __launch_bounds__(256) void proj_kernel(const float* __restrict__ bp,
                                                   float* __restrict__ out) {
  __shared__ float pr[NH];
  int b = blockIdx.x, o = threadIdx.x;
  pr[o] = g_pool[b*NH + o];
  pr[o+256] = g_pool[b*NH + 256 + o];
  __syncthreads();
  float acc = bp[o];
  #pragma unroll 8
  for (int u = 0; u < NH; ++u) acc = fmaf(pr[u], g_Wt[u*256 + o], acc);
  out[b*256 + o] = 0.5f*acc*(1.f + erff(acc*0.70710678118654752f));
}

extern "C" void kernel_launch(void* const* d_in, const int* in_sizes, int n_in,
                              void* d_out, int out_size, void* d_ws, size_t ws_size,
                              hipStream_t stream) {
  const float* x    = (const float*)d_in[0];
  const int*   mask = (const int*)d_in[1];
  const float* Wih0 = (const float*)d_in[2];
  const float* Whh0 = (const float*)d_in[3];
  const float* bih0 = (const float*)d_in[4];
  const float* bhh0 = (const float*)d_in[5];
  const float* Wih1 = (const float*)d_in[6];
  const float* Whh1 = (const float*)d_in[7];
  const float* bih1 = (const float*)d_in[8];
  const float* bhh1 = (const float*)d_in[9];
  const float* lng  = (const float*)d_in[10];
  const float* lnb  = (const float*)d_in[11];
  const float* Wp   = (const float*)d_in[12];
  const float* bp   = (const float*)d_in[13];
  float* out = (float*)d_out;
  (void)in_sizes; (void)n_in; (void)out_size; (void)d_ws; (void)ws_size;

  hipFuncSetAttribute(reinterpret_cast<const void*>(gru_main),
                      hipFuncAttributeMaxDynamicSharedMemorySize, 161792);

  hipLaunchKernelGGL(init_kernel, dim3(2048), dim3(256), 0, stream, Wp, x, mask);
  hipLaunchKernelGGL(gru_main, dim3(256), dim3(256), 161792, stream,
                     Wih0, Whh0, bih0, bhh0, Wih1, Whh1, bih1, bhh1, lng, lnb);
  hipLaunchKernelGGL(proj_kernel, dim3(NB), dim3(256), 0, stream, bp, out);
}